// Round 14
// baseline (142.541 us; speedup 1.0000x reference)
//
#include <hip/hip_runtime.h>
#include <hip/hip_bf16.h>
#include <cstdint>
#include <cstddef>

typedef __attribute__((ext_vector_type(8))) short short8;
typedef __attribute__((ext_vector_type(4))) float f32x4;

static constexpr int M_TOT = 31744;
static constexpr int N_TOT = 1152;
static constexpr int K_TOT = 768;
static constexpr long A_ELEMS = (long)M_TOT * K_TOT;   // 24379392
static constexpr long W_ELEMS = (long)N_TOT * K_TOT;   // 884736
static constexpr int CYC_ROWS = 3968;                  // one ragged cycle (4 images)

__device__ __forceinline__ unsigned short f2bf(float f) {
  unsigned int u = __float_as_uint(f);
  u += 0x7FFFu + ((u >> 16) & 1u);   // round-to-nearest-even
  return (unsigned short)(u >> 16);
}
__device__ __forceinline__ float bf2f(unsigned short u) {
  return __uint_as_float((unsigned int)u << 16);
}

// ---------------- prep: cvt A&W (blocks < 12336) + pos table (rest) ----------------
__global__ void prep_kernel(const float* __restrict__ A, const float* __restrict__ W,
                            const float* __restrict__ pos, const float* __restrict__ bias,
                            unsigned short* __restrict__ dst, unsigned short* __restrict__ tab) {
  const int b = blockIdx.x;
  if (b < 12336) {   // fp32 -> bf16 for A then W (r7-verbatim logic)
    long i = ((long)b * 256 + threadIdx.x) * 8;
    const float* src = (i < A_ELEMS) ? (A + i) : (W + (i - A_ELEMS));
    float4 v0 = *(const float4*)(src);
    float4 v1 = *(const float4*)(src + 4);
    short8 o;
    o[0] = (short)f2bf(v0.x); o[1] = (short)f2bf(v0.y);
    o[2] = (short)f2bf(v0.z); o[3] = (short)f2bf(v0.w);
    o[4] = (short)f2bf(v1.x); o[5] = (short)f2bf(v1.y);
    o[6] = (short)f2bf(v1.z); o[7] = (short)f2bf(v1.w);
    *(short8*)(dst + i) = o;
    return;
  }
  const int t = (b - 12336) * 256 + threadIdx.x;   // 571392 = 3968 * 144
  const int row = t / 144;
  const int dc = (t - row * 144) * 8;

  int rr, cc; float sy, sx;
  if (row < 1024)      { rr = row >> 5; cc = row & 31; sy = 0.5f;         sx = 0.5f; }
  else if (row < 2048) { const int li = row - 1024; rr = li >> 6; cc = li & 63; sy = 1.0f; sx = 0.25f; }
  else if (row < 3008) { const int li = row - 2048; rr = li / 40; cc = li - rr * 40; sy = 16.0f / 24.0f; sx = 0.4f; }
  else                 { const int li = row - 3008; rr = li / 24; cc = li - rr * 24; sy = 0.4f; sx = 16.0f / 24.0f; }
  float yc = fminf(fmaxf(((float)rr + 0.5f) * sy - 0.5f, 0.0f), 15.0f);
  const int y0 = (int)yc; const float fy = yc - (float)y0;
  const int y1 = y0 < 15 ? y0 + 1 : 15;
  float xc = fminf(fmaxf(((float)cc + 0.5f) * sx - 0.5f, 0.0f), 15.0f);
  const int x0 = (int)xc; const float fx = xc - (float)x0;
  const int x1 = x0 < 15 ? x0 + 1 : 15;
  const float w11 = fy * fx;
  const float w10 = fy - w11;
  const float w01 = fx - w11;
  const float w00 = 1.0f - fy - fx + w11;
  const float* p00 = pos + (size_t)(y0 * 16 + x0) * 1152 + dc;
  const float* p01 = pos + (size_t)(y0 * 16 + x1) * 1152 + dc;
  const float* p10 = pos + (size_t)(y1 * 16 + x0) * 1152 + dc;
  const float* p11 = pos + (size_t)(y1 * 16 + x1) * 1152 + dc;
  const float* bi  = bias + dc;
  short8 o;
#pragma unroll
  for (int j = 0; j < 8; ++j) {
    const float v = bi[j] + w00 * p00[j] + w01 * p01[j] + w10 * p10[j] + w11 * p11[j];
    o[j] = (short)f2bf(v);
  }
  *(short8*)(tab + (size_t)row * 1152 + dc) = o;
}

__device__ __forceinline__ void gload_lds16(const void* g, void* l) {
  __builtin_amdgcn_global_load_lds((__attribute__((address_space(1))) void*)g,
                                   (__attribute__((address_space(3))) void*)l, 16, 0, 0);
}

// ---------------- pass 2: BARRIER-FREE wave-private double-buffered GEMM ----------
// 128x128 tile, BK=32, 24 K-steps, 256 threads = 4 waves (2x2), wave-tile 64x64.
// Each wave stages its OWN A rows (wr*64..+63) and B rows (wc*64..+63) into a
// wave-private 8 KB LDS region (A 4KB + B 4KB), double-buffered -> NO s_barrier
// anywhere. Sync = per-wave counted vmcnt(8) only. Same-wave DS ordering makes
// the buffer swap race-free (ds_read issues before the next gload's return can
// reach LDS); sched_barrier(0) per iter stops compiler hoisting across it.
// LDS 2 bufs x 4 waves x 8 KB = 64 KB -> 2 blocks/CU (8 waves, 2/SIMD).
__global__ __launch_bounds__(256, 2) void gemm_kernel(
    const unsigned short* __restrict__ Abf, const unsigned short* __restrict__ Wbf,
    const unsigned short* __restrict__ tab, float* __restrict__ outp) {
  __shared__ __attribute__((aligned(16))) unsigned short Lds[2 * 4 * 4096];  // 64 KB

  // XCD-bijective swizzle: 2232 tiles = 8 XCDs * 279 (r5/r7-proven).
  const int bid = blockIdx.x;
  const int tile = (bid & 7) * 279 + (bid >> 3);
  const int tm = tile / 9, tn = tile % 9;   // 248 x 9 tiles of 128x128
  const int m0 = tm * 128, n0 = tn * 128;

  const int tid = threadIdx.x;
  const int w = tid >> 6, lane = tid & 63;
  const int wr = w >> 1, wc = w & 1;        // 2x2 waves, 64x64 each
  const int kg = lane >> 4, l15 = lane & 15;

  // staging lane map (r7-proven): row = base + (lane>>2), chunk = lane&3,
  // source chunk pre-swizzled by key (row>>1)&3 = (lane>>3)&3.
  const int srow = lane >> 2;
  const int schunk = ((lane & 3) ^ ((lane >> 3) & 3)) * 8;
  const unsigned short* Asrc = Abf + (size_t)(m0 + wr * 64 + srow) * K_TOT + schunk;
  const unsigned short* Bsrc = Wbf + (size_t)(n0 + wc * 64 + srow) * K_TOT + schunk;
  char* const myLds = (char*)Lds + w * 8192;          // wave-private region (buf 0)

  const int rkey = (l15 >> 1) & 3;          // ds_read swizzle key (r7-proven, 0 conflicts)

  f32x4 acc[4][4] = {};

#define STAGE(p_, kt)                                                            \
  { char* rg_ = myLds + (p_) * 32768;                                            \
    const int k0_ = (kt) * 32;                                                   \
    gload_lds16(Asrc + k0_,                      rg_);                           \
    gload_lds16(Asrc + (size_t)16 * K_TOT + k0_, rg_ + 1024);                    \
    gload_lds16(Asrc + (size_t)32 * K_TOT + k0_, rg_ + 2048);                    \
    gload_lds16(Asrc + (size_t)48 * K_TOT + k0_, rg_ + 3072);                    \
    gload_lds16(Bsrc + k0_,                      rg_ + 4096);                    \
    gload_lds16(Bsrc + (size_t)16 * K_TOT + k0_, rg_ + 5120);                    \
    gload_lds16(Bsrc + (size_t)32 * K_TOT + k0_, rg_ + 6144);                    \
    gload_lds16(Bsrc + (size_t)48 * K_TOT + k0_, rg_ + 7168); }

#define COMPUTE(p_)                                                              \
  { const char* rg_ = myLds + (p_) * 32768;                                      \
    short8 fa[4], fb[4];                                                         \
    _Pragma("unroll") for (int m = 0; m < 4; ++m)                                \
      fa[m] = *(const short8*)(rg_ + (m * 16 + l15) * 64 + ((kg ^ rkey) << 4));  \
    _Pragma("unroll") for (int n = 0; n < 4; ++n)                                \
      fb[n] = *(const short8*)(rg_ + 4096 + (n * 16 + l15) * 64 +                \
                               ((kg ^ rkey) << 4));                              \
    __builtin_amdgcn_s_setprio(1);                                               \
    _Pragma("unroll") for (int m = 0; m < 4; ++m)                                \
      _Pragma("unroll") for (int n = 0; n < 4; ++n)                              \
        acc[m][n] = __builtin_amdgcn_mfma_f32_16x16x32_bf16(                     \
            fa[m], fb[n], acc[m][n], 0, 0, 0);                                   \
    __builtin_amdgcn_s_setprio(0); }

  // prologue: stage tile 0 into buf 0 (8 loads in flight)
  STAGE(0, 0)

  for (int t = 0; t < 24; ++t) {
    const int p = t & 1;
    __builtin_amdgcn_sched_barrier(0);   // keep prior ds_reads below next stage
    if (t < 23) {
      STAGE(p ^ 1, t + 1)                // 8 new loads; tile t's 8 are oldest
      asm volatile("s_waitcnt vmcnt(8)" ::: "memory");   // retire tile t only
    } else {
      asm volatile("s_waitcnt vmcnt(0)" ::: "memory");
    }
    COMPUTE(p)                           // no barrier: wave-private data
  }

#undef STAGE
#undef COMPUTE

  // ---------------- epilogue (r5/r7-verified): out = acc + tab[s % 3968, d] ----
  const int s_base = m0 + wr * 64 + ((lane >> 4) << 2);  // + m*16 + r
  const int rem_base = s_base % CYC_ROWS;
  const int d_base = n0 + wc * 64 + l15;                 // + n*16

#pragma unroll
  for (int m = 0; m < 4; ++m) {
#pragma unroll
    for (int r = 0; r < 4; ++r) {
      const int off = m * 16 + r;
      int rem = rem_base + off;
      if (rem >= CYC_ROWS) rem -= CYC_ROWS;
      const unsigned short* trow = tab + (size_t)rem * 1152 + d_base;
      float* orow = outp + (size_t)(s_base + off) * 1152 + d_base;
#pragma unroll
      for (int n = 0; n < 4; ++n)
        orow[n * 16] = acc[m][n][r] + bf2f(trow[n * 16]);
    }
  }
}

extern "C" void kernel_launch(void* const* d_in, const int* in_sizes, int n_in,
                              void* d_out, int out_size, void* d_ws, size_t ws_size,
                              hipStream_t stream) {
  const float* A    = (const float*)d_in[0];  // seq_patches [31744,768]
  const float* W    = (const float*)d_in[1];  // w [1152,768]
  const float* bias = (const float*)d_in[2];  // b [1152]
  const float* pos  = (const float*)d_in[3];  // pos_emb [256,1152]
  unsigned short* Abf = (unsigned short*)d_ws;            // 48.76 MB
  unsigned short* Wbf = Abf + A_ELEMS;                    // +1.77 MB
  unsigned short* tab = Wbf + W_ELEMS;                    // +9.14 MB
  float* outp = (float*)d_out;

  // 12336 cvt blocks + 2232 tab blocks = 14568
  prep_kernel<<<14568, 256, 0, stream>>>(A, W, pos, bias, Abf, tab);
  gemm_kernel<<<2232, 256, 0, stream>>>(Abf, Wbf, tab, outp);
}